// Round 1
// 260.304 us; speedup vs baseline: 1.0296x; 1.0296x over previous
//
#include <hip/hip_runtime.h>
#include <hip/hip_bf16.h>
#include <cstdint>
#include <cstddef>

#define DEV __device__ __forceinline__

typedef __attribute__((ext_vector_type(8))) short  s8v;    // 8 bf16 (4 VGPR)
typedef __attribute__((ext_vector_type(4))) float  f4v;    // MFMA acc / 16B f32 load
typedef __attribute__((ext_vector_type(4))) uint32_t u4v;  // 16B packed store

// ---------- bf16 helpers ----------
DEV unsigned short f2bf(float x) {                 // RNE bithack (host-independent path)
  union { float f; uint32_t u; } v; v.f = x;
  uint32_t u = v.u + 0x7FFFu + ((v.u >> 16) & 1u);
  return (unsigned short)(u >> 16);
}
// HW packed convert: 2 f32 -> u32 of 2 bf16 (RNE, identical to f2bf)
DEV uint32_t cvtpk2(float lo, float hi) {
  uint32_t r;
  asm("v_cvt_pk_bf16_f32 %0, %1, %2" : "=v"(r) : "v"(lo), "v"(hi));
  return r;
}
DEV unsigned short f2bf_fast(float x) { return (unsigned short)cvtpk2(x, 0.f); }
DEV float bf2f(unsigned short b) {
  union { uint32_t u; float f; } v; v.u = ((uint32_t)b) << 16;
  return v.f;
}

// ---------- async global->LDS 16B (dest = wave-uniform base + lane*16) ----------
DEV void async_copy16(void* lds, const void* g) {
  typedef __attribute__((address_space(3))) uint32_t lds_t;
  typedef const __attribute__((address_space(1))) uint32_t g_t;
  __builtin_amdgcn_global_load_lds((g_t*)g, (lds_t*)lds, 16, 0, 0);
}

// counted-vmcnt pipeline waits (raw s_barrier, no compiler vmcnt(0) drain)
#define WAITV8()    asm volatile("s_waitcnt vmcnt(8)" ::: "memory")
#define WAITV0()    asm volatile("s_waitcnt vmcnt(0)" ::: "memory")
#define WAITLGKM0() asm volatile("s_waitcnt lgkmcnt(0)" ::: "memory")

constexpr int Bc = 32, Oc = 256, Tc = 1024;
constexpr int BM = 128, BN = 128, BK = 64;
constexpr int BUFSZ = BM * BK * 2 + BN * BK * 2;   // 32 KiB per K-tile buffer
constexpr int CSR_CAP = 46;   // max degree per (b,o); P(exceed) ~ 1e-19

// bijective XCD chunk swizzle + n-inner decomposition.
DEV void swz_mn(int nyb, int* mb, int* nb) {
  const int nwg = gridDim.x * gridDim.y;            // multiple of 8 for all uses
  const int w   = blockIdx.x + blockIdx.y * gridDim.x;
  const int cpx = nwg >> 3;
  const int s   = (w & 7) * cpx + (w >> 3);
  *mb = s / nyb;
  *nb = s % nyb;
}

// ---------------------------------------------------------------------------
// fp32 -> bf16 bulk convert, 8 elems/thread, 16B stores
// ---------------------------------------------------------------------------
__global__ __launch_bounds__(256)
void cvt_k(const float* __restrict__ in, unsigned short* __restrict__ outp, int n8)
{
  const int i = blockIdx.x * 256 + threadIdx.x;
  if (i >= n8) return;
  const f4v v0 = *(const f4v*)(in + (size_t)i * 8);
  const f4v v1 = *(const f4v*)(in + (size_t)i * 8 + 4);
  u4v pk;
  pk.x = cvtpk2(v0.x, v0.y);
  pk.y = cvtpk2(v0.z, v0.w);
  pk.z = cvtpk2(v1.x, v1.y);
  pk.w = cvtpk2(v1.z, v1.w);
  *(u4v*)(outp + (size_t)i * 8) = pk;
}

// ---------------------------------------------------------------------------
// GEMM1: gathered-A bf16 GEMM. A row m = [objb[s(m)], predb[m], objb[o(m)]]
// M=32768 N=512 K=1536. Depth-2 double-buffered, counted vmcnt(8).
// ---------------------------------------------------------------------------
__global__ __launch_bounds__(256)
void gemm1_k(const unsigned short* __restrict__ objb,
             const unsigned short* __restrict__ predb,
             const int* __restrict__ edges,
             const unsigned short* __restrict__ Bt,   // (512,1536) bf16
             const float* __restrict__ bias,
             unsigned short* __restrict__ outp)       // (32768,512) bf16
{
  __shared__ __align__(16) char smem[2 * BUFSZ];      // 64 KiB: 2 K-tile buffers

  const int tid  = threadIdx.x;
  const int lane = tid & 63;
  const int wave = tid >> 6;
  const int wm = wave >> 1, wn = wave & 1;
  int mb, nb; swz_mn(gridDim.y, &mb, &nb);
  const int m0 = mb * BM;
  const int n0 = nb * BN;
  const int r8  = lane >> 3;
  const int cs8 = ((lane & 7) ^ r8) * 8;   // inverse-swizzled col chunk (elements)

  // per-lane gathered A row pointers (region 0 = obj[s], 1 = pred, 2 = obj[o])
  const unsigned short *aS0, *aS1, *aS2, *aS3;
  const unsigned short *aO0, *aO1, *aO2, *aO3;
  const unsigned short *aP0, *aP1, *aP2, *aP3;
#define MKP(i, PS, PO, PP) do { \
    const int m = m0 + wave * 32 + (i) * 8 + r8; \
    const int ob = (m >> 10) * Oc; \
    PS = objb + ((size_t)(ob + edges[2 * m])) * 512 + cs8; \
    PO = objb + ((size_t)(ob + edges[2 * m + 1])) * 512 + cs8; \
    PP = predb + (size_t)m * 512 + cs8; \
  } while (0)
  MKP(0, aS0, aO0, aP0); MKP(1, aS1, aO1, aP1);
  MKP(2, aS2, aO2, aP2); MKP(3, aS3, aO3, aP3);
#undef MKP
  const unsigned short* bsrc = Bt + (size_t)(n0 + wave * 32 + r8) * 1536 + cs8;

  f4v acc[4][4] = {};

  auto compute = [&](const char* As, const char* Bs) {
    #pragma unroll
    for (int kk = 0; kk < 2; ++kk) {
      s8v af[4], bfv[4];
      #pragma unroll
      for (int i = 0; i < 4; ++i) {
        const int row = wm * 64 + i * 16 + (lane & 15);
        const int c = kk * 4 + (lane >> 4);
        af[i] = *(const s8v*)(As + row * 128 + ((c ^ (row & 7)) << 4));
      }
      #pragma unroll
      for (int j = 0; j < 4; ++j) {
        const int row = wn * 64 + j * 16 + (lane & 15);
        const int c = kk * 4 + (lane >> 4);
        bfv[j] = *(const s8v*)(Bs + row * 128 + ((c ^ (row & 7)) << 4));
      }
      #pragma unroll
      for (int i = 0; i < 4; ++i)
        #pragma unroll
        for (int j = 0; j < 4; ++j)
          acc[i][j] = __builtin_amdgcn_mfma_f32_16x16x32_bf16(af[i], bfv[j], acc[i][j], 0, 0, 0);
    }
  };

  // stage K-tile kt (kt in [0,24)) into buffer buf. 8 loads/wave.
  auto stage = [&](int buf, int kt) {
    char* As = smem + buf * BUFSZ;
    char* Bs = As + BM * BK * 2;
    const unsigned short* b = bsrc + kt * 64;        // B k-cols are contiguous
    async_copy16(Bs + (wave * 32 +  0) * 128, b);
    async_copy16(Bs + (wave * 32 +  8) * 128, b + 8 * 1536);
    async_copy16(Bs + (wave * 32 + 16) * 128, b + 16 * 1536);
    async_copy16(Bs + (wave * 32 + 24) * 128, b + 24 * 1536);
    const int kin = (kt & 7) * 64;
    const unsigned short *p0, *p1, *p2, *p3;
    if (kt < 8)       { p0 = aS0; p1 = aS1; p2 = aS2; p3 = aS3; }
    else if (kt < 16) { p0 = aP0; p1 = aP1; p2 = aP2; p3 = aP3; }
    else              { p0 = aO0; p1 = aO1; p2 = aO2; p3 = aO3; }
    async_copy16(As + (wave * 32 +  0) * 128, p0 + kin);
    async_copy16(As + (wave * 32 +  8) * 128, p1 + kin);
    async_copy16(As + (wave * 32 + 16) * 128, p2 + kin);
    async_copy16(As + (wave * 32 + 24) * 128, p3 + kin);
  };

  constexpr int NK = 24;
  stage(0, 0);
  stage(1, 1);
  for (int kt = 0; kt < NK; ++kt) {
    // tile kt's 8 loads are the oldest; tile kt+1's 8 stay in flight.
    if (kt + 1 < NK) WAITV8(); else WAITV0();
    __builtin_amdgcn_s_barrier();
    const int b = kt & 1;
    compute(smem + b * BUFSZ, smem + b * BUFSZ + BM * BK * 2);
    // all ds_reads of buf b must COMPLETE (not just issue) before any wave
    // can overwrite it after the barrier.
    WAITLGKM0();
    __builtin_amdgcn_sched_barrier(0);
    __builtin_amdgcn_s_barrier();
    if (kt + 2 < NK) stage(b, kt + 2);   // overwrite fully-consumed buffer
  }

  // epilogue: C/D layout col=lane&15, row=(lane>>4)*4+r
  const int cn = lane & 15, rq4 = (lane >> 4) * 4;
  #pragma unroll
  for (int i = 0; i < 4; ++i) {
    const int gr0 = m0 + wm * 64 + i * 16 + rq4;
    #pragma unroll
    for (int j = 0; j < 4; ++j) {
      const int gc = n0 + wn * 64 + j * 16 + cn;
      const float bv = bias[gc];
      #pragma unroll
      for (int r = 0; r < 4; ++r) {
        float val = acc[i][j][r] + bv;
        val = val > 0.f ? val : 0.f;
        outp[(size_t)(gr0 + r) * 512 + gc] = f2bf_fast(val);
      }
    }
  }
}

// ---------------------------------------------------------------------------
// Generic 128x128 bf16 GEMM, A (M,K) bf16, Bt (N,K) bf16.
// Depth-2 double-buffered, counted vmcnt(8).
// EPI: 0 = relu->bf16 (stride N); 1 = relu*conf -> split s/p/o; 2 = relu->f32
// ---------------------------------------------------------------------------
template<int EPI>
__global__ __launch_bounds__(256)
void gemm_k(const unsigned short* __restrict__ Abf,
            const unsigned short* __restrict__ Bt,
            const float* __restrict__ bias,
            const float* __restrict__ conf,
            unsigned short* __restrict__ out_bf,
            float* __restrict__ out_f32,
            unsigned short* __restrict__ out_bf2,
            int M, int N, int K)
{
  __shared__ __align__(16) char smem[2 * BUFSZ];    // 64 KiB

  const int tid  = threadIdx.x;
  const int lane = tid & 63;
  const int wave = tid >> 6;
  const int wm = wave >> 1, wn = wave & 1;
  int mb, nb; swz_mn(gridDim.y, &mb, &nb);
  const int m0 = mb * BM;
  const int n0 = nb * BN;
  const int r8 = lane >> 3;
  const int cs = (lane & 7) ^ r8;

  const unsigned short* srcb = Bt  + (size_t)(n0 + wave * 32 + r8) * K + cs * 8;
  const unsigned short* srca = Abf + (size_t)(m0 + wave * 32 + r8) * K + cs * 8;

  f4v acc[4][4] = {};

  auto compute = [&](const char* As, const char* Bs) {
    #pragma unroll
    for (int kk = 0; kk < 2; ++kk) {
      s8v af[4], bfv[4];
      #pragma unroll
      for (int i = 0; i < 4; ++i) {
        const int row = wm * 64 + i * 16 + (lane & 15);
        const int c = kk * 4 + (lane >> 4);
        af[i] = *(const s8v*)(As + row * 128 + ((c ^ (row & 7)) << 4));
      }
      #pragma unroll
      for (int j = 0; j < 4; ++j) {
        const int row = wn * 64 + j * 16 + (lane & 15);
        const int c = kk * 4 + (lane >> 4);
        bfv[j] = *(const s8v*)(Bs + row * 128 + ((c ^ (row & 7)) << 4));
      }
      #pragma unroll
      for (int i = 0; i < 4; ++i)
        #pragma unroll
        for (int j = 0; j < 4; ++j)
          acc[i][j] = __builtin_amdgcn_mfma_f32_16x16x32_bf16(af[i], bfv[j], acc[i][j], 0, 0, 0);
    }
  };

  auto stage = [&](int buf, int k0) {
    char* As = smem + buf * BUFSZ;
    char* Bs = As + BM * BK * 2;
    #pragma unroll
    for (int i = 0; i < 4; ++i)
      async_copy16(Bs + (wave * 32 + i * 8) * 128, srcb + k0 + (size_t)(i * 8) * K);
    #pragma unroll
    for (int i = 0; i < 4; ++i)
      async_copy16(As + (wave * 32 + i * 8) * 128, srca + k0 + (size_t)(i * 8) * K);
  };

  const int nk = K / BK;                 // >= 8 for all uses
  stage(0, 0);
  stage(1, BK);
  for (int kt = 0; kt < nk; ++kt) {
    if (kt + 1 < nk) WAITV8(); else WAITV0();
    __builtin_amdgcn_s_barrier();
    const int b = kt & 1;
    compute(smem + b * BUFSZ, smem + b * BUFSZ + BM * BK * 2);
    WAITLGKM0();
    __builtin_amdgcn_sched_barrier(0);
    __builtin_amdgcn_s_barrier();
    if (kt + 2 < nk) stage(b, (kt + 2) * BK);
  }

  const int cn = lane & 15, rq4 = (lane >> 4) * 4;
  #pragma unroll
  for (int i = 0; i < 4; ++i) {
    const int gr0 = m0 + wm * 64 + i * 16 + rq4;
    #pragma unroll
    for (int j = 0; j < 4; ++j) {
      const int gc = n0 + wn * 64 + j * 16 + cn;
      const float bv = bias[gc];
      #pragma unroll
      for (int r = 0; r < 4; ++r) {
        float val = acc[i][j][r] + bv;
        val = val > 0.f ? val : 0.f;
        const int gr = gr0 + r;
        if (EPI == 0) {
          out_bf[(size_t)gr * N + gc] = f2bf_fast(val);
        } else if (EPI == 1) {
          val *= conf[gr];
          if (gc < 512)        out_bf [(size_t)gr * 512 + gc]          = f2bf_fast(val);
          else if (gc < 1024)  out_f32[(size_t)gr * 512 + (gc - 512)]  = val;
          else                 out_bf2[(size_t)gr * 512 + (gc - 1024)] = f2bf_fast(val);
        } else {
          out_f32[(size_t)gr * N + gc] = val;
        }
      }
    }
  }
}

// ---------------------------------------------------------------------------
// W (K x N fp32) -> Wt (N x K bf16)
// ---------------------------------------------------------------------------
__global__ void tcvt_k(const float* __restrict__ W, unsigned short* __restrict__ Wt,
                       int K, int N)
{
  __shared__ float tile[32][33];
  const int k0 = blockIdx.x * 32, n0 = blockIdx.y * 32;
  const int tx = threadIdx.x, ty = threadIdx.y;
  #pragma unroll
  for (int i = 0; i < 32; i += 8)
    tile[ty + i][tx] = W[(size_t)(k0 + ty + i) * N + (n0 + tx)];
  __syncthreads();
  #pragma unroll
  for (int i = 0; i < 32; i += 8)
    Wt[(size_t)(n0 + ty + i) * K + (k0 + tx)] = f2bf(tile[tx][ty + i]);
}

// ---------------------------------------------------------------------------
__global__ void detect_k(const unsigned char* __restrict__ mb, int* __restrict__ flag)
{
  __shared__ int any;
  if (threadIdx.x == 0) any = 0;
  __syncthreads();
  int local = 0;
  for (int i = threadIdx.x; i < Bc * Tc; i += 256)
    if ((i & 3) && mb[i]) local = 1;
  if (local) atomicOr(&any, 1);
  __syncthreads();
  if (threadIdx.x == 0) *flag = any;
}

__global__ void prep_k(const int* __restrict__ tt, const int* __restrict__ pid,
                       const float* __restrict__ ptw, const int* __restrict__ edges,
                       const void* __restrict__ mask, const int* __restrict__ u8flag,
                       float* __restrict__ conf, int* __restrict__ se, int* __restrict__ oe)
{
  const int m = blockIdx.x * 256 + threadIdx.x;
  const int t = tt[m];
  float c = 0.f;
  if (t == 0) c = 1.f;
  else if (t == 1) c = 1.f / (1.f + expf(-ptw[pid[m]]));
  conf[m] = c;
  bool mk;
  if (*u8flag) mk = ((const unsigned char*)mask)[m] != 0;
  else         mk = ((const int*)mask)[m] != 0;
  se[m] = mk ? edges[2 * m]     : -1;
  oe[m] = mk ? edges[2 * m + 1] : -1;
}

// ---------------------------------------------------------------------------
// Wave-parallel CSR build: one wave per (b,o). Deterministic via ballot rank.
// ---------------------------------------------------------------------------
__global__ __launch_bounds__(256)
void csr2_k(const int* __restrict__ se, const int* __restrict__ oe,
            int* __restrict__ deg, int* __restrict__ slot)
{
  const int wid  = blockIdx.x * 4 + (threadIdx.x >> 6);  // (b<<8)|u
  const int b    = wid >> 8;
  const int u    = wid & 255;
  const int lane = threadIdx.x & 63;
  const int mb   = b * Tc;
  int* sl = slot + (size_t)wid * CSR_CAP;
  const unsigned long long lt = (1ull << lane) - 1ull;
  int cnt = 0;
  #pragma unroll 4
  for (int c = 0; c < 16; ++c) {
    const int t = c * 64 + lane;
    const int s = se[mb + t];
    const int o = oe[mb + t];
    const unsigned long long ms = __ballot(s == u);
    const unsigned long long mo = __ballot(o == u);
    if (s == u) {
      const int pos = cnt + (int)__popcll(ms & lt);
      if (pos < CSR_CAP) sl[pos] = 2 * t;
    }
    cnt += (int)__popcll(ms);
    if (o == u) {
      const int pos = cnt + (int)__popcll(mo & lt);
      if (pos < CSR_CAP) sl[pos] = 2 * t + 1;
    }
    cnt += (int)__popcll(mo);
  }
  if (lane == 0) deg[wid] = cnt < CSR_CAP ? cnt : CSR_CAP;
}

// ---------------------------------------------------------------------------
// CSR pool: one block per (b, o); thread u handles cols 2u, 2u+1 (4B loads).
// ---------------------------------------------------------------------------
__global__ __launch_bounds__(256)
void pool2_k(const unsigned short* __restrict__ S, const unsigned short* __restrict__ Ov,
             const int* __restrict__ deg, const int* __restrict__ slot,
             const float* __restrict__ conf,
             unsigned short* __restrict__ pooled)
{
  const int bo = blockIdx.x;            // b*256 + o
  const int b  = bo >> 8;
  const int u  = threadIdx.x;
  const int d  = deg[bo];
  const int* sl = slot + (size_t)bo * CSR_CAP;
  float a0 = 0.f, a1 = 0.f, w = 0.f;
  for (int i = 0; i < d; ++i) {
    const int e = sl[i];                // uniform load
    const int t = e >> 1;
    const unsigned short* row = ((e & 1) ? Ov : S) + ((size_t)(b * Tc + t)) * 512;
    const uint32_t pr = *(const uint32_t*)(row + 2 * u);
    a0 += bf2f((unsigned short)pr);
    a1 += bf2f((unsigned short)(pr >> 16));
    w  += conf[b * Tc + t];
  }
  const float denom = (w > 0.f) ? w : 1.f;
  const size_t ob = (size_t)bo * 512;
  *(uint32_t*)(pooled + ob + 2 * u) = cvtpk2(a0 / denom, a1 / denom);
}

// ---------------------------------------------------------------------------
extern "C" void kernel_launch(void* const* d_in, const int* in_sizes, int n_in,
                              void* d_out, int out_size, void* d_ws, size_t ws_size,
                              hipStream_t stream)
{
  const float* obj  = (const float*)d_in[0];
  const float* pred = (const float*)d_in[1];
  const float* W1a  = (const float*)d_in[2];
  const float* b1a  = (const float*)d_in[3];
  const float* W1b  = (const float*)d_in[4];
  const float* b1b  = (const float*)d_in[5];
  const float* W2a  = (const float*)d_in[6];
  const float* b2a  = (const float*)d_in[7];
  const float* W2b  = (const float*)d_in[8];
  const float* b2b  = (const float*)d_in[9];
  const float* ptw  = (const float*)d_in[10];
  const int*   edges = (const int*)d_in[11];
  const void*  mask  = d_in[12];
  const int*   tt    = (const int*)d_in[13];
  const int*   pid   = (const int*)d_in[14];
  float* out = (float*)d_out;

  char* ws = (char*)d_ws;
  // [0, 4194304): transposed bf16 weights.
  // W1at [0, 1572864) is DEAD after gemm1 -> reused for CSR deg+slot.
  unsigned short* W1at = (unsigned short*)(ws + 0);          // 512x1536
  unsigned short* W1bt = (unsigned short*)(ws + 1572864);    // 1536x512
  unsigned short* W2at = (unsigned short*)(ws + 3145728);    // 512x512
  unsigned short* W2bt = (unsigned short*)(ws + 3670016);    // 512x512
  int* deg  = (int*)(ws + 0);                                // 8192 ints
  int* slot = (int*)(ws + 32768);                            // 8192*46 ints
  unsigned short* h    = (unsigned short*)(ws + 4194304);    // 32768x512 bf16, 32MB
  unsigned short* pooled = h;                                // 8192x512 (post-GEMM2)
  unsigned short* h2   = (unsigned short*)(ws + 12582912);   // 8192x512 bf16
  unsigned short* news = (unsigned short*)(ws + 37748736);   // 32768x512 bf16
  unsigned short* newo = (unsigned short*)(ws + 71303168);   // 32768x512 bf16
  unsigned short* objb = news;                               // 32x256x512 (pre-GEMM2)
  unsigned short* predb = (unsigned short*)(ws + 46137344);  // 32x1024x512 (pre-GEMM2)
  float* conf = (float*)(ws + 104857600);
  int*   se   = (int*)(ws + 104988672);
  int*   oe   = (int*)(ws + 105119744);
  int* u8flag = (int*)(ws + 105250816);

  // weight transpose+convert
  tcvt_k<<<dim3(48, 16), dim3(32, 8), 0, stream>>>(W1a, W1at, 1536, 512);
  tcvt_k<<<dim3(16, 48), dim3(32, 8), 0, stream>>>(W1b, W1bt, 512, 1536);
  tcvt_k<<<dim3(16, 16), dim3(32, 8), 0, stream>>>(W2a, W2at, 512, 512);
  tcvt_k<<<dim3(16, 16), dim3(32, 8), 0, stream>>>(W2b, W2bt, 512, 512);

  // fp32 -> bf16 sources for the gathered GEMM1
  cvt_k<<<2048, 256, 0, stream>>>(obj,  objb,  Bc * Oc * 512 / 8);
  cvt_k<<<8192, 256, 0, stream>>>(pred, predb, Bc * Tc * 512 / 8);

  detect_k<<<1, 256, 0, stream>>>((const unsigned char*)mask, u8flag);
  prep_k<<<128, 256, 0, stream>>>(tt, pid, ptw, edges, mask, u8flag, conf, se, oe);

  // GEMM1: gather folded into staging; (32768x1536)@(1536x512) -> h
  gemm1_k<<<dim3(256, 4), 256, 0, stream>>>(objb, predb, edges, W1at, b1a, h);

  // wave-parallel CSR build (reuses W1at space — dead now)
  csr2_k<<<2048, 256, 0, stream>>>(se, oe, deg, slot);

  // GEMM2: h @ W1b -> relu*conf -> split new_s / new_p(d_out) / new_o
  gemm_k<1><<<dim3(256, 12), 256, 0, stream>>>(
      h, W1bt, b1b, conf, news, out + 4194304, newo, 32768, 1536, 512);

  // CSR pool -> pooled (bf16, 8192x512)
  pool2_k<<<Bc * Oc, 256, 0, stream>>>(news, newo, deg, slot, conf, pooled);

  // GEMM3: pooled @ W2a -> h2
  gemm_k<0><<<dim3(64, 4), 256, 0, stream>>>(
      pooled, W2at, b2a, nullptr, h2, nullptr, nullptr, 8192, 512, 512);

  // GEMM4: h2 @ W2b -> new_obj (f32, d_out)
  gemm_k<2><<<dim3(64, 4), 256, 0, stream>>>(
      h2, W2bt, b2b, nullptr, nullptr, out, nullptr, 8192, 512, 512);
}